// Round 3
// baseline (159.937 us; speedup 1.0000x reference)
//
#include <hip/hip_runtime.h>

#define B_ 2048
#define S_ 512
#define T_ 17
#define REC 40
#define MAINB 64     // 32 fwd + 32 bwd blocks (256 thr = 4 waves, 16 seqs/wave)
#define HELPB 512    // 4 seqs per helper block (1 per wave)

// DPP quad rotations: dst lane l reads lane (l+r)&3 of its quad
#define QROT1(x) __int_as_float(__builtin_amdgcn_update_dpp(0, __float_as_int(x), 0x39, 0xF, 0xF, true))
#define QROT2(x) __int_as_float(__builtin_amdgcn_update_dpp(0, __float_as_int(x), 0x4E, 0xF, 0xF, true))
#define QROT3(x) __int_as_float(__builtin_amdgcn_update_dpp(0, __float_as_int(x), 0x93, 0xF, 0xF, true))

#define GATHERM(SRC) do {                                                   \
    _Pragma("unroll")                                                       \
    for (int k_ = 0; k_ < 5; ++k_) {                                        \
        g[k_]      = SRC[k_];                                               \
        g[5 + k_]  = QROT1(SRC[k_]);                                        \
        g[10 + k_] = QROT2(SRC[k_]);                                        \
        g[15 + k_] = QROT3(SRC[k_]);                                        \
    }                                                                       \
} while (0)

#define DOTSM() do {                                                        \
    _Pragma("unroll") for (int k_ = 0; k_ < 5; ++k_) acc[k_] = 0.0f;        \
    _Pragma("unroll") for (int ri_ = 0; ri_ < 20; ++ri_) {                  \
        _Pragma("unroll") for (int k_ = 0; k_ < 5; ++k_)                    \
            acc[k_] = fmaf(g[ri_], C[ri_ * 5 + k_], acc[k_]);               \
    }                                                                       \
} while (0)

#define MAX20M(M) do {                                                      \
    float x0=fmaxf(g[0],g[1]),  x1=fmaxf(g[2],g[3]),  x2=fmaxf(g[4],g[5]);  \
    float x3=fmaxf(g[6],g[7]),  x4=fmaxf(g[8],g[9]),  x5=fmaxf(g[10],g[11]);\
    float x6=fmaxf(g[12],g[13]),x7=fmaxf(g[14],g[15]);                      \
    float x8=fmaxf(g[16],g[17]),x9=fmaxf(g[18],g[19]);                      \
    M = fmaxf(fmaxf(fmaxf(x0,x1),fmaxf(x2,x3)),                             \
        fmaxf(fmaxf(x4,x5),fmaxf(fmaxf(x6,x7),fmaxf(x8,x9))));              \
} while (0)

// forward step: w'_j = (sum_i w_i E_ij) * d_j, mask-gated, optional renorm
#define FSTEPM(L0,L1,L2,L3,L4, MI, RN) do {                                 \
    float g[20]; GATHERM(w);                                                \
    float acc[5]; DOTSM();                                                  \
    float rinv_ = 1.0f;                                                     \
    if (RN) { float M_; MAX20M(M_); rinv_ = 1.0f / M_; Z += __logf(M_); }   \
    float dd[5] = {__expf(L0),__expf(L1),__expf(L2),__expf(L3),__expf(L4)}; \
    bool bm_ = (MI) != 0;                                                   \
    _Pragma("unroll") for (int k_ = 0; k_ < 5; ++k_) {                      \
        float wn_ = acc[k_] * dd[k_];                                       \
        float sel_ = bm_ ? wn_ : w[k_];                                     \
        w[k_] = (RN) ? sel_ * rinv_ : sel_;                                 \
    }                                                                       \
} while (0)

// backward step: v'_i = sum_j E_ij (d_j v_j), mask-gated, optional renorm
#define BSTEPM(L0,L1,L2,L3,L4, MI, RN) do {                                 \
    float dd[5] = {__expf(L0),__expf(L1),__expf(L2),__expf(L3),__expf(L4)}; \
    float uu[5];                                                            \
    _Pragma("unroll") for (int k_ = 0; k_ < 5; ++k_) uu[k_] = w[k_]*dd[k_]; \
    float g[20]; GATHERM(uu);                                               \
    float acc[5]; DOTSM();                                                  \
    float rinv_ = 1.0f;                                                     \
    if (RN) { float M_; MAX20M(M_); rinv_ = 1.0f / M_; Z += __logf(M_); }   \
    bool bm_ = (MI) != 0;                                                   \
    _Pragma("unroll") for (int k_ = 0; k_ < 5; ++k_) {                      \
        float sel_ = bm_ ? acc[k_] : w[k_];                                 \
        w[k_] = (RN) ? sel_ * rinv_ : sel_;                                 \
    }                                                                       \
} while (0)

#define FCHUNK4(BUF, MV, RN0) do {                                          \
    FSTEPM(BUF[0], BUF[1], BUF[2], BUF[3], BUF[4],  (MV).x, RN0);           \
    FSTEPM(BUF[5], BUF[6], BUF[7], BUF[8], BUF[9],  (MV).y, false);         \
    FSTEPM(BUF[10],BUF[11],BUF[12],BUF[13],BUF[14], (MV).z, false);         \
    FSTEPM(BUF[15],BUF[16],BUF[17],BUF[18],BUF[19], (MV).w, false);         \
} while (0)

#define BCHUNK4(BUF, MV) do {                                               \
    BSTEPM(BUF[15],BUF[16],BUF[17],BUF[18],BUF[19], (MV).w, true);          \
    BSTEPM(BUF[10],BUF[11],BUF[12],BUF[13],BUF[14], (MV).z, false);         \
    BSTEPM(BUF[5], BUF[6], BUF[7], BUF[8], BUF[9],  (MV).y, false);         \
    BSTEPM(BUF[0], BUF[1], BUF[2], BUF[3], BUF[4],  (MV).x, false);         \
} while (0)

#define LOADCHUNK(BUF, ROWBASE) do {                                        \
    const float* rp_ = ipb + (size_t)(ROWBASE) * T_;                        \
    _Pragma("unroll") for (int v_ = 0; v_ < 4; ++v_) {                      \
        _Pragma("unroll") for (int k_ = 0; k_ < 5; ++k_)                    \
            BUF[v_ * 5 + k_] = rp_[v_ * T_ + stk[k_]];                      \
    }                                                                       \
} while (0)

__global__ __launch_bounds__(256, 1) void crf_fused(
    const float* __restrict__ inputs,   // [B,S,T]
    const int*   __restrict__ tags,     // [B,S]
    const int*   __restrict__ mask,     // [B,S]
    const float* __restrict__ trans,    // [T,T]
    const float* __restrict__ startt,   // [T]
    const float* __restrict__ endt,     // [T]
    float* __restrict__ ws)             // [B][REC]
{
    __shared__ float tl[T_ * T_];
    __shared__ float Ep[T_ * T_];
    const int tid = (int)threadIdx.x;
    const int bid = (int)blockIdx.x;
    for (int idx = tid; idx < T_ * T_; idx += 256) {
        float tv = trans[idx];
        tl[idx] = tv;
        Ep[idx] = __expf(tv);
    }
    __syncthreads();

    const int wv = tid >> 6;
    const int lane = tid & 63;

    if (bid < MAINB) {
        // ================= MAIN: scaled fwd/bwd recurrence =================
        const bool isF = (bid < 32);
        const int q = lane >> 2;
        const int l = lane & 3;
        const int seq = (isF ? bid : bid - 32) * 64 + wv * 16 + q;

        // lane's 5 states (lane 3: 13,14,15,16,16-dup; dups killed by coeffs)
        int stk[5];
#pragma unroll
        for (int k = 0; k < 5; ++k)
            stk[k] = (l == 3) ? (k < 4 ? 13 + k : 16) : 5 * l + k;

        // 100 coefficient regs: C[(r*5+i)*5+k] = E contribution of
        // (source lane (l+r)&3, source reg i) to lane's output reg k.
        float C[100];
#pragma unroll
        for (int r = 0; r < 4; ++r) {
            const int sl = (l + r) & 3;
#pragma unroll
            for (int i = 0; i < 5; ++i) {
                const int si = (sl == 3) ? (i < 4 ? 13 + i : 16) : 5 * sl + i;
                const bool canon = (sl < 3) || (i == 2) || (i == 3);
#pragma unroll
                for (int k = 0; k < 5; ++k) {
                    const int dj = stk[k];
                    C[(r * 5 + i) * 5 + k] =
                        canon ? (isF ? Ep[si * T_ + dj] : Ep[dj * T_ + si]) : 0.0f;
                }
            }
        }

        const float* ipb = inputs + (size_t)seq * (S_ * T_);
        const int4* mp4c = (const int4*)(mask + (size_t)seq * S_);

        float w[5], Z = 0.0f;
        float bufA[20], bufB[20];
        int4 mA, mB;

        if (isF) {
            LOADCHUNK(bufA, 0);   mA = mp4c[0];
            LOADCHUNK(bufB, 4);   mB = mp4c[1];
#pragma unroll
            for (int k = 0; k < 5; ++k) w[k] = __expf(bufA[k] + startt[stk[k]]);
            FSTEPM(bufA[5], bufA[6], bufA[7], bufA[8], bufA[9],  mA.y, false);
            FSTEPM(bufA[10],bufA[11],bufA[12],bufA[13],bufA[14], mA.z, false);
            FSTEPM(bufA[15],bufA[16],bufA[17],bufA[18],bufA[19], mA.w, false);
            LOADCHUNK(bufA, 8);   mA = mp4c[2];
            for (int it = 0; it < 31; ++it) {
                FCHUNK4(bufB, mB, true);                    // chunk 1+2it
                int cn = 3 + 2 * it;
                if (cn < 64) { LOADCHUNK(bufB, 4 * cn); mB = mp4c[cn]; }
                FCHUNK4(bufA, mA, true);                    // chunk 2+2it
                int cn2 = 4 + 2 * it;
                if (cn2 < 64) { LOADCHUNK(bufA, 4 * cn2); mA = mp4c[cn2]; }
            }
            FCHUNK4(bufB, mB, true);                        // chunk 63 -> alpha_255
            float* rec = ws + (size_t)seq * REC;
#pragma unroll
            for (int k = 0; k < 5; ++k)
                if ((l < 3) || (k == 2) || (k == 3)) rec[stk[k]] = w[k];
            if (l == 0) rec[17] = Z;
        } else {
            LOADCHUNK(bufA, 508); mA = mp4c[127];
            LOADCHUNK(bufB, 504); mB = mp4c[126];
#pragma unroll
            for (int k = 0; k < 5; ++k) w[k] = __expf(endt[stk[k]]);
            for (int it = 0; it < 31; ++it) {
                BCHUNK4(bufA, mA);                          // chunk 2it
                int cn = 2 * it + 2;
                if (cn < 64) { LOADCHUNK(bufA, 508 - 4 * cn); mA = mp4c[127 - cn]; }
                BCHUNK4(bufB, mB);                          // chunk 2it+1
                int cn2 = 2 * it + 3;
                if (cn2 < 64) { LOADCHUNK(bufB, 508 - 4 * cn2); mB = mp4c[127 - cn2]; }
            }
            BCHUNK4(bufA, mA);                              // chunk 62
            BCHUNK4(bufB, mB);                              // chunk 63 -> v_255
            float* rec = ws + (size_t)seq * REC + 18;
#pragma unroll
            for (int k = 0; k < 5; ++k)
                if ((l < 3) || (k == 2) || (k == 3)) rec[stk[k]] = w[k];
            if (l == 0) rec[17] = Z;                        // ws[..+35]
        }
    } else {
        // ================= HELPER: per-seq path score =================
        const int s = (bid - MAINB) * 4 + wv;
        const int* tp = tags + (size_t)s * S_;
        const int* mp = mask + (size_t)s * S_;
        const float* ib = inputs + (size_t)s * (S_ * T_);
        const int4* tp4 = (const int4*)tp;
        const int4* mp4 = (const int4*)mp;

        int4 t0 = tp4[2 * lane], t1 = tp4[2 * lane + 1];
        int4 m0 = mp4[2 * lane], m1 = mp4[2 * lane + 1];
        int tg[8] = {t0.x, t0.y, t0.z, t0.w, t1.x, t1.y, t1.z, t1.w};
        int mi[8] = {m0.x, m0.y, m0.z, m0.w, m1.x, m1.y, m1.z, m1.w};
        int tprev = (lane > 0) ? tp[8 * lane - 1] : 0;

        float e = 0.0f, tr = 0.0f;
        int ms = 0;
#pragma unroll
        for (int u = 0; u < 8; ++u) {
            int t = 8 * lane + u;
            float mf = (float)mi[u];
            float gate = (t <= S_ - 2) ? mf : 0.0f;
            e = fmaf(gate, ib[(size_t)t * T_ + tg[u]], e);
            int pt = (u == 0) ? tprev : tg[u - 1];
            float tv = tl[pt * T_ + tg[u]];
            tr = fmaf((t >= 1) ? mf : 0.0f, tv, tr);
            ms += mi[u];
        }
        for (int d = 1; d < 64; d <<= 1) {
            e  += __shfl_xor(e, d);
            tr += __shfl_xor(tr, d);
            ms += __shfl_xor(ms, d);
        }
        if (lane == 0) {
            int li = ms - 1; if (li < 0) li = 0;
            int lt = tp[li];
            float ml = (float)mp[S_ - 1];
            float lin = ib[(size_t)(S_ - 1) * T_ + lt];
            float sc = startt[tp[0]] + tr + e + endt[lt] + lin * ml;
            ws[(size_t)s * REC + 36] = sc;
        }
    }
}

__global__ __launch_bounds__(256) void crf_final(const float* __restrict__ ws,
                                                 float* __restrict__ out)
{
    __shared__ float sm[256];
    const int tid = (int)threadIdx.x;
    float a = 0.0f;
    for (int s = tid; s < B_; s += 256) {
        const float* r = ws + (size_t)s * REC;
        float dot = 0.0f;
#pragma unroll
        for (int i = 0; i < T_; ++i) dot = fmaf(r[i], r[18 + i], dot);
        a += r[36] - (r[17] + r[35] + __logf(dot));
    }
    sm[tid] = a;
    __syncthreads();
    for (int k = 128; k >= 1; k >>= 1) {
        if (tid < k) sm[tid] += sm[tid + k];
        __syncthreads();
    }
    if (tid == 0) out[0] = sm[0];
}

extern "C" void kernel_launch(void* const* d_in, const int* in_sizes, int n_in,
                              void* d_out, int out_size, void* d_ws, size_t ws_size,
                              hipStream_t stream)
{
    const float* inputs = (const float*)d_in[0];
    const int*   tags   = (const int*)d_in[1];
    const int*   mask   = (const int*)d_in[2];
    const float* trans  = (const float*)d_in[3];
    const float* startt = (const float*)d_in[4];
    const float* endt   = (const float*)d_in[5];
    float* out = (float*)d_out;
    float* ws  = (float*)d_ws;

    crf_fused<<<MAINB + HELPB, 256, 0, stream>>>(inputs, tags, mask, trans,
                                                 startt, endt, ws);
    crf_final<<<1, 256, 0, stream>>>(ws, out);
}

// Round 4
// 132.338 us; speedup vs baseline: 1.2086x; 1.2086x over previous
//
#include <hip/hip_runtime.h>

#define B_ 2048
#define S_ 512
#define T_ 17
#define REC 40
#define FWDB 171
#define MAINB 342        // 171 fwd + 171 bwd waves, 12 seqs each
#define SEQW 12

// ---- load one 4-step chunk: logits (lane's state j, 4 seqs) + masks ----
#define LOADC(LG, MK, T0) do {                                              \
    _Pragma("unroll") for (int k_ = 0; k_ < 4; ++k_) {                      \
        const float* rp_ = ipk[k_] + (size_t)(T0) * T_;                     \
        _Pragma("unroll") for (int u_ = 0; u_ < 4; ++u_)                    \
            LG[u_ * 4 + k_] = rp_[u_ * T_];                                 \
        const int4 mv_ = *(const int4*)(mpk[k_] + (T0));                    \
        MK[0 * 4 + k_] = mv_.x; MK[1 * 4 + k_] = mv_.y;                     \
        MK[2 * 4 + k_] = mv_.z; MK[3 * 4 + k_] = mv_.w;                     \
    }                                                                       \
} while (0)

#define DDC(DD, LG) do {                                                    \
    _Pragma("unroll") for (int x_ = 0; x_ < 16; ++x_) DD[x_] = __expf(LG[x_]); \
} while (0)

// forward step for 4 seqs: w'_j = (sum_i w_i E_ij) * d_j, mask-gated
#define FSTEPM(D0,D1,D2,D3, M0,M1,M2,M3, RN) do {                           \
    __builtin_amdgcn_wave_barrier();                                        \
    wbuf4[g * T_ + j] = wv;                                                 \
    __builtin_amdgcn_wave_barrier();                                        \
    float4 acc = {0.f,0.f,0.f,0.f}; float4 Mv = {0.f,0.f,0.f,0.f};          \
    _Pragma("unroll") for (int i_ = 0; i_ < T_; ++i_) {                     \
        float4 gv_ = wbuf4[g * T_ + i_];                                    \
        acc.x = fmaf(gv_.x, Ec[i_], acc.x); acc.y = fmaf(gv_.y, Ec[i_], acc.y); \
        acc.z = fmaf(gv_.z, Ec[i_], acc.z); acc.w = fmaf(gv_.w, Ec[i_], acc.w); \
        if (RN) { Mv.x = fmaxf(Mv.x, gv_.x); Mv.y = fmaxf(Mv.y, gv_.y);     \
                  Mv.z = fmaxf(Mv.z, gv_.z); Mv.w = fmaxf(Mv.w, gv_.w); }   \
    }                                                                       \
    __builtin_amdgcn_wave_barrier();                                        \
    if (RN) {                                                               \
        float rx_=1.0f/Mv.x, ry_=1.0f/Mv.y, rz_=1.0f/Mv.z, rw_=1.0f/Mv.w;   \
        Zv.x += __logf(Mv.x); Zv.y += __logf(Mv.y);                         \
        Zv.z += __logf(Mv.z); Zv.w += __logf(Mv.w);                         \
        wv.x = ((M0) ? acc.x * (D0) : wv.x) * rx_;                          \
        wv.y = ((M1) ? acc.y * (D1) : wv.y) * ry_;                          \
        wv.z = ((M2) ? acc.z * (D2) : wv.z) * rz_;                          \
        wv.w = ((M3) ? acc.w * (D3) : wv.w) * rw_;                          \
    } else {                                                                \
        wv.x = (M0) ? acc.x * (D0) : wv.x;                                  \
        wv.y = (M1) ? acc.y * (D1) : wv.y;                                  \
        wv.z = (M2) ? acc.z * (D2) : wv.z;                                  \
        wv.w = (M3) ? acc.w * (D3) : wv.w;                                  \
    }                                                                       \
} while (0)

// backward step for 4 seqs: v'_i = sum_j E_ij (d_j v_j), mask-gated
#define BSTEPM(D0,D1,D2,D3, M0,M1,M2,M3, RN) do {                           \
    float4 uv_;                                                             \
    uv_.x = wv.x * (D0); uv_.y = wv.y * (D1);                               \
    uv_.z = wv.z * (D2); uv_.w = wv.w * (D3);                               \
    __builtin_amdgcn_wave_barrier();                                        \
    wbuf4[g * T_ + j] = uv_;                                                \
    __builtin_amdgcn_wave_barrier();                                        \
    float4 acc = {0.f,0.f,0.f,0.f}; float4 Mv = {0.f,0.f,0.f,0.f};          \
    _Pragma("unroll") for (int i_ = 0; i_ < T_; ++i_) {                     \
        float4 gv_ = wbuf4[g * T_ + i_];                                    \
        acc.x = fmaf(gv_.x, Ec[i_], acc.x); acc.y = fmaf(gv_.y, Ec[i_], acc.y); \
        acc.z = fmaf(gv_.z, Ec[i_], acc.z); acc.w = fmaf(gv_.w, Ec[i_], acc.w); \
        if (RN) { Mv.x = fmaxf(Mv.x, gv_.x); Mv.y = fmaxf(Mv.y, gv_.y);     \
                  Mv.z = fmaxf(Mv.z, gv_.z); Mv.w = fmaxf(Mv.w, gv_.w); }   \
    }                                                                       \
    __builtin_amdgcn_wave_barrier();                                        \
    if (RN) {                                                               \
        float rx_=1.0f/Mv.x, ry_=1.0f/Mv.y, rz_=1.0f/Mv.z, rw_=1.0f/Mv.w;   \
        Zv.x += __logf(Mv.x); Zv.y += __logf(Mv.y);                         \
        Zv.z += __logf(Mv.z); Zv.w += __logf(Mv.w);                         \
        wv.x = ((M0) ? acc.x : wv.x) * rx_;                                 \
        wv.y = ((M1) ? acc.y : wv.y) * ry_;                                 \
        wv.z = ((M2) ? acc.z : wv.z) * rz_;                                 \
        wv.w = ((M3) ? acc.w : wv.w) * rw_;                                 \
    } else {                                                                \
        wv.x = (M0) ? acc.x : wv.x;                                         \
        wv.y = (M1) ? acc.y : wv.y;                                         \
        wv.z = (M2) ? acc.z : wv.z;                                         \
        wv.w = (M3) ? acc.w : wv.w;                                         \
    }                                                                       \
} while (0)

#define FCH(DD, MK, RN0) do {                                               \
    FSTEPM(DD[0], DD[1], DD[2], DD[3],  MK[0], MK[1], MK[2], MK[3],  RN0);  \
    FSTEPM(DD[4], DD[5], DD[6], DD[7],  MK[4], MK[5], MK[6], MK[7],  false);\
    FSTEPM(DD[8], DD[9], DD[10],DD[11], MK[8], MK[9], MK[10],MK[11], false);\
    FSTEPM(DD[12],DD[13],DD[14],DD[15], MK[12],MK[13],MK[14],MK[15], false);\
} while (0)

#define BCH(DD, MK) do {                                                    \
    BSTEPM(DD[12],DD[13],DD[14],DD[15], MK[12],MK[13],MK[14],MK[15], true); \
    BSTEPM(DD[8], DD[9], DD[10],DD[11], MK[8], MK[9], MK[10],MK[11], false);\
    BSTEPM(DD[4], DD[5], DD[6], DD[7],  MK[4], MK[5], MK[6], MK[7],  false);\
    BSTEPM(DD[0], DD[1], DD[2], DD[3],  MK[0], MK[1], MK[2], MK[3],  false);\
} while (0)

__global__ __launch_bounds__(64, 1) void crf_fused(
    const float* __restrict__ inputs,   // [B,S,T]
    const int*   __restrict__ tags,     // [B,S]
    const int*   __restrict__ mask,     // [B,S]
    const float* __restrict__ trans,    // [T,T]
    const float* __restrict__ startt,   // [T]
    const float* __restrict__ endt,     // [T]
    float* __restrict__ ws)             // [B][REC]
{
    __shared__ float tl[T_ * T_];
    __shared__ __align__(16) float4 wbuf4[4 * T_];

    const int lane = (int)threadIdx.x;
    const int bid = (int)blockIdx.x;
    for (int k = lane; k < T_ * T_; k += 64) tl[k] = trans[k];
    __syncthreads();

    if (bid < MAINB) {
        // ============ MAIN: scaled fwd/bwd recurrence, 12 seqs/wave ============
        const bool isF = (bid < FWDB);
        const int seg = isF ? bid : bid - FWDB;
        int g = lane / T_;                 // 0..3 (3 = 13 idle lanes)
        const int j = lane - g * T_;       // state 0..16
        const int gi = (g < 3) ? g : 2;

        int sq[4]; bool valid[4];
        const float* ipk[4]; const int* mpk[4];
#pragma unroll
        for (int k = 0; k < 4; ++k) {
            int s = seg * SEQW + gi * 4 + k;
            valid[k] = (g < 3) && (s < B_);
            sq[k] = (s < B_) ? s : (B_ - 1);
            ipk[k] = inputs + (size_t)sq[k] * (S_ * T_) + j;
            mpk[k] = mask + (size_t)sq[k] * S_;
        }

        // fwd lane j: column j of E=exp(trans); bwd lane j: row j
        float Ec[T_];
#pragma unroll
        for (int i = 0; i < T_; ++i)
            Ec[i] = __expf(isF ? tl[i * T_ + j] : tl[j * T_ + i]);

        float LA[16], LB[16], DD[16];
        int MA[16], MB[16];
        float4 wv, Zv = {0.f, 0.f, 0.f, 0.f};

        if (isF) {
            LOADC(LA, MA, 0);
            LOADC(LB, MB, 4);
            const float stj = startt[j];
            wv.x = __expf(LA[0] + stj); wv.y = __expf(LA[1] + stj);
            wv.z = __expf(LA[2] + stj); wv.w = __expf(LA[3] + stj);
            DDC(DD, LA);
            FSTEPM(DD[4], DD[5], DD[6], DD[7],  MA[4], MA[5], MA[6], MA[7],  false);
            FSTEPM(DD[8], DD[9], DD[10],DD[11], MA[8], MA[9], MA[10],MA[11], false);
            FSTEPM(DD[12],DD[13],DD[14],DD[15], MA[12],MA[13],MA[14],MA[15], false);
            for (int c = 1; c < 64; ++c) {
#pragma unroll
                for (int x = 0; x < 16; ++x) { LA[x] = LB[x]; MA[x] = MB[x]; }
                if (c < 63) LOADC(LB, MB, 4 * (c + 1));
                DDC(DD, LA);
                FCH(DD, MA, true);
            }
            // wv = scaled alpha_255, Zv = log-scales
#pragma unroll
            for (int k = 0; k < 4; ++k)
                if (valid[k]) {
                    float wvk = (k==0)?wv.x:(k==1)?wv.y:(k==2)?wv.z:wv.w;
                    ws[(size_t)sq[k] * REC + j] = wvk;
                }
            if (j == 0) {
#pragma unroll
                for (int k = 0; k < 4; ++k)
                    if (valid[k]) {
                        float zk = (k==0)?Zv.x:(k==1)?Zv.y:(k==2)?Zv.z:Zv.w;
                        ws[(size_t)sq[k] * REC + 17] = zk;
                    }
            }
        } else {
            LOADC(LA, MA, 508);
            LOADC(LB, MB, 504);
            const float ev = __expf(endt[j]);
            wv.x = ev; wv.y = ev; wv.z = ev; wv.w = ev;     // v_{511}
            DDC(DD, LA);
            BCH(DD, MA);                                     // t = 511..508
            for (int c = 1; c < 64; ++c) {
#pragma unroll
                for (int x = 0; x < 16; ++x) { LA[x] = LB[x]; MA[x] = MB[x]; }
                if (c < 63) LOADC(LB, MB, 508 - 4 * (c + 1));
                DDC(DD, LA);
                BCH(DD, MA);                                 // down to t = 256
            }
#pragma unroll
            for (int k = 0; k < 4; ++k)
                if (valid[k]) {
                    float wvk = (k==0)?wv.x:(k==1)?wv.y:(k==2)?wv.z:wv.w;
                    ws[(size_t)sq[k] * REC + 18 + j] = wvk;
                }
            if (j == 0) {
#pragma unroll
                for (int k = 0; k < 4; ++k)
                    if (valid[k]) {
                        float zk = (k==0)?Zv.x:(k==1)?Zv.y:(k==2)?Zv.z:Zv.w;
                        ws[(size_t)sq[k] * REC + 35] = zk;
                    }
            }
        }
    } else {
        // ============ HELPER: per-seq path score (1 seq / wave) ============
        const int s = bid - MAINB;
        const int* tp = tags + (size_t)s * S_;
        const int* mp = mask + (size_t)s * S_;
        const float* ib = inputs + (size_t)s * (S_ * T_);
        const int4* tp4 = (const int4*)tp;
        const int4* mp4 = (const int4*)mp;

        int4 t0 = tp4[2 * lane], t1 = tp4[2 * lane + 1];
        int4 m0 = mp4[2 * lane], m1 = mp4[2 * lane + 1];
        int tg[8] = {t0.x, t0.y, t0.z, t0.w, t1.x, t1.y, t1.z, t1.w};
        int mi[8] = {m0.x, m0.y, m0.z, m0.w, m1.x, m1.y, m1.z, m1.w};
        int tprev = (lane > 0) ? tp[8 * lane - 1] : 0;

        float e = 0.0f, tr = 0.0f;
        int ms = 0;
#pragma unroll
        for (int u = 0; u < 8; ++u) {
            int t = 8 * lane + u;
            float mf = (float)mi[u];
            float gate = (t <= S_ - 2) ? mf : 0.0f;
            e = fmaf(gate, ib[(size_t)t * T_ + tg[u]], e);
            int pt = (u == 0) ? tprev : tg[u - 1];
            float tv = tl[pt * T_ + tg[u]];
            tr = fmaf((t >= 1) ? mf : 0.0f, tv, tr);
            ms += mi[u];
        }
        for (int d = 1; d < 64; d <<= 1) {
            e  += __shfl_xor(e, d);
            tr += __shfl_xor(tr, d);
            ms += __shfl_xor(ms, d);
        }
        if (lane == 0) {
            int li = ms - 1; if (li < 0) li = 0;
            int lt = tp[li];
            float ml = (float)mp[S_ - 1];
            float lin = ib[(size_t)(S_ - 1) * T_ + lt];
            float sc = startt[tp[0]] + tr + e + endt[lt] + lin * ml;
            ws[(size_t)s * REC + 36] = sc;
        }
    }
}

__global__ __launch_bounds__(256) void crf_final(const float* __restrict__ ws,
                                                 float* __restrict__ out)
{
    __shared__ float sm[256];
    const int tid = (int)threadIdx.x;
    float a = 0.0f;
    for (int s = tid; s < B_; s += 256) {
        const float* r = ws + (size_t)s * REC;
        float dot = 0.0f;
#pragma unroll
        for (int i = 0; i < T_; ++i) dot = fmaf(r[i], r[18 + i], dot);
        a += r[36] - (r[17] + r[35] + __logf(dot));
    }
    sm[tid] = a;
    __syncthreads();
    for (int k = 128; k >= 1; k >>= 1) {
        if (tid < k) sm[tid] += sm[tid + k];
        __syncthreads();
    }
    if (tid == 0) out[0] = sm[0];
}

extern "C" void kernel_launch(void* const* d_in, const int* in_sizes, int n_in,
                              void* d_out, int out_size, void* d_ws, size_t ws_size,
                              hipStream_t stream)
{
    const float* inputs = (const float*)d_in[0];
    const int*   tags   = (const int*)d_in[1];
    const int*   mask   = (const int*)d_in[2];
    const float* trans  = (const float*)d_in[3];
    const float* startt = (const float*)d_in[4];
    const float* endt   = (const float*)d_in[5];
    float* out = (float*)d_out;
    float* ws  = (float*)d_ws;

    crf_fused<<<MAINB + B_, 64, 0, stream>>>(inputs, tags, mask, trans,
                                             startt, endt, ws);
    crf_final<<<1, 256, 0, stream>>>(ws, out);
}

// Round 5
// 82.804 us; speedup vs baseline: 1.9315x; 1.5982x over previous
//
#include <hip/hip_runtime.h>

#define B_ 2048
#define S_ 512
#define T_ 17
#define REC 40
#define FWDB 342
#define MAINB 684        // 342 fwd + 342 bwd waves, 6 seqs each (3 groups x 2 chains)
#define SEQW 6

#define DOT17(S, q0,q1,q2,q3,q16) do {                                            \
    S = (fmaf((q0).x,Ec[0],fmaf((q0).y,Ec[1],fmaf((q0).z,Ec[2],(q0).w*Ec[3])))    \
      +  fmaf((q1).x,Ec[4],fmaf((q1).y,Ec[5],fmaf((q1).z,Ec[6],(q1).w*Ec[7]))))   \
      + (fmaf((q2).x,Ec[8],fmaf((q2).y,Ec[9],fmaf((q2).z,Ec[10],(q2).w*Ec[11])))  \
      +  fmaf((q3).x,Ec[12],fmaf((q3).y,Ec[13],fmaf((q3).z,Ec[14],(q3).w*Ec[15]))))\
      + (q16)*Ec[16];                                                             \
} while (0)

#define MAXQ(M, q0,q1,q2,q3,q16) do {                                             \
    M = fmaxf(fmaxf(fmaxf(fmaxf((q0).x,(q0).y),fmaxf((q0).z,(q0).w)),             \
                    fmaxf(fmaxf((q1).x,(q1).y),fmaxf((q1).z,(q1).w))),            \
        fmaxf(fmaxf(fmaxf((q2).x,(q2).y),fmaxf((q2).z,(q2).w)),                   \
              fmaxf(fmaxf(fmaxf((q3).x,(q3).y),fmaxf((q3).z,(q3).w)),(q16))));    \
} while (0)

// two forward steps (chains A,B) interleaved: A's LDS latency hides under B's issue
#define FSTEP2(U, RN) do {                                                        \
    __builtin_amdgcn_wave_barrier();                                              \
    slA[j] = wA;                                                                  \
    __builtin_amdgcn_wave_barrier();                                              \
    float4 a0_=slA4[0], a1_=slA4[1], a2_=slA4[2], a3_=slA4[3]; float a16_=slA[16];\
    __builtin_amdgcn_wave_barrier();                                              \
    slB[j] = wB;                                                                  \
    __builtin_amdgcn_wave_barrier();                                              \
    float4 b0_=slB4[0], b1_=slB4[1], b2_=slB4[2], b3_=slB4[3]; float b16_=slB[16];\
    __builtin_amdgcn_wave_barrier();                                              \
    float sA_, sB_;                                                               \
    DOT17(sA_, a0_,a1_,a2_,a3_,a16_);                                             \
    DOT17(sB_, b0_,b1_,b2_,b3_,b16_);                                             \
    float nA_ = (CM[0][U]) ? sA_ * DD[0][U] : wA;                                 \
    float nB_ = (CM[1][U]) ? sB_ * DD[1][U] : wB;                                 \
    if (RN) {                                                                     \
        float MA_, MB_;                                                           \
        MAXQ(MA_, a0_,a1_,a2_,a3_,a16_);                                          \
        MAXQ(MB_, b0_,b1_,b2_,b3_,b16_);                                          \
        ZA += __logf(MA_); ZB += __logf(MB_);                                     \
        wA = nA_ * (1.0f / MA_); wB = nB_ * (1.0f / MB_);                         \
    } else { wA = nA_; wB = nB_; }                                                \
} while (0)

// two backward steps: v'_i = sum_j E_ij (d_j v_j)
#define BSTEP2(U, RN) do {                                                        \
    float uA_ = wA * DD[0][U], uB_ = wB * DD[1][U];                               \
    __builtin_amdgcn_wave_barrier();                                              \
    slA[j] = uA_;                                                                 \
    __builtin_amdgcn_wave_barrier();                                              \
    float4 a0_=slA4[0], a1_=slA4[1], a2_=slA4[2], a3_=slA4[3]; float a16_=slA[16];\
    __builtin_amdgcn_wave_barrier();                                              \
    slB[j] = uB_;                                                                 \
    __builtin_amdgcn_wave_barrier();                                              \
    float4 b0_=slB4[0], b1_=slB4[1], b2_=slB4[2], b3_=slB4[3]; float b16_=slB[16];\
    __builtin_amdgcn_wave_barrier();                                              \
    float sA_, sB_;                                                               \
    DOT17(sA_, a0_,a1_,a2_,a3_,a16_);                                             \
    DOT17(sB_, b0_,b1_,b2_,b3_,b16_);                                             \
    float nA_ = (CM[0][U]) ? sA_ : wA;                                            \
    float nB_ = (CM[1][U]) ? sB_ : wB;                                            \
    if (RN) {                                                                     \
        float MA_, MB_;                                                           \
        MAXQ(MA_, a0_,a1_,a2_,a3_,a16_);                                          \
        MAXQ(MB_, b0_,b1_,b2_,b3_,b16_);                                          \
        ZA += __logf(MA_); ZB += __logf(MB_);                                     \
        wA = nA_ * (1.0f / MA_); wB = nB_ * (1.0f / MB_);                         \
    } else { wA = nA_; wB = nB_; }                                                \
} while (0)

#define LOADC(LG, MK, T0) do {                                                    \
    _Pragma("unroll") for (int u_ = 0; u_ < 8; ++u_) {                            \
        LG[0][u_] = ipA[(size_t)((T0) + u_) * T_];                                \
        LG[1][u_] = ipB[(size_t)((T0) + u_) * T_];                                \
    }                                                                             \
    int4 xa0_ = mpA[(T0) >> 2], xa1_ = mpA[((T0) >> 2) + 1];                      \
    int4 xb0_ = mpB[(T0) >> 2], xb1_ = mpB[((T0) >> 2) + 1];                      \
    MK[0][0]=xa0_.x; MK[0][1]=xa0_.y; MK[0][2]=xa0_.z; MK[0][3]=xa0_.w;           \
    MK[0][4]=xa1_.x; MK[0][5]=xa1_.y; MK[0][6]=xa1_.z; MK[0][7]=xa1_.w;           \
    MK[1][0]=xb0_.x; MK[1][1]=xb0_.y; MK[1][2]=xb0_.z; MK[1][3]=xb0_.w;           \
    MK[1][4]=xb1_.x; MK[1][5]=xb1_.y; MK[1][6]=xb1_.z; MK[1][7]=xb1_.w;           \
} while (0)

#define COPYNC() do {                                                             \
    _Pragma("unroll") for (int x_ = 0; x_ < 8; ++x_) {                            \
        CL[0][x_] = NL[0][x_]; CL[1][x_] = NL[1][x_];                             \
        CM[0][x_] = NM[0][x_]; CM[1][x_] = NM[1][x_];                             \
    }                                                                             \
} while (0)

#define DDC() do {                                                                \
    _Pragma("unroll") for (int x_ = 0; x_ < 8; ++x_) {                            \
        DD[0][x_] = __expf(CL[0][x_]); DD[1][x_] = __expf(CL[1][x_]);             \
    }                                                                             \
} while (0)

__global__ __launch_bounds__(64, 2) void crf_fused(
    const float* __restrict__ inputs,   // [B,S,T]
    const int*   __restrict__ tags,     // [B,S]
    const int*   __restrict__ mask,     // [B,S]
    const float* __restrict__ trans,    // [T,T]
    const float* __restrict__ startt,   // [T]
    const float* __restrict__ endt,     // [T]
    float* __restrict__ ws)             // [B][REC]
{
    __shared__ float tl[T_ * T_];
    __shared__ __align__(16) float wsl[2][80];   // [chain][group*20 + j]

    const int lane = (int)threadIdx.x;
    const int bid = (int)blockIdx.x;
    for (int k = lane; k < T_ * T_; k += 64) tl[k] = trans[k];
    __syncthreads();

    if (bid < MAINB) {
        // ======== MAIN: scaled fwd/bwd recurrence, 2-chain ILP ========
        const bool isF = (bid < FWDB);
        const int seg = isF ? bid : bid - FWDB;
        int g = lane / T_;                 // 0..3 (3 = 13 idle lanes, own slot)
        const int j = lane - g * T_;       // state 0..16
        const int gi = (g < 3) ? g : 2;

        const int sA = seg * SEQW + gi * 2;
        const int sB = sA + 1;
        const bool vA = (g < 3) && (sA < B_);
        const bool vB = (g < 3) && (sB < B_);
        const int qA = (sA < B_) ? sA : (B_ - 1);
        const int qB = (sB < B_) ? sB : (B_ - 1);

        const float* ipA = inputs + (size_t)qA * (S_ * T_) + j;
        const float* ipB = inputs + (size_t)qB * (S_ * T_) + j;
        const int4* mpA = (const int4*)(mask + (size_t)qA * S_);
        const int4* mpB = (const int4*)(mask + (size_t)qB * S_);

        // fwd lane j: column j of E=exp(trans); bwd lane j: row j
        float Ec[T_];
#pragma unroll
        for (int i = 0; i < T_; ++i)
            Ec[i] = __expf(isF ? tl[i * T_ + j] : tl[j * T_ + i]);

        float* slA = &wsl[0][g * 20];
        float* slB = &wsl[1][g * 20];
        const float4* slA4 = (const float4*)slA;
        const float4* slB4 = (const float4*)slB;

        float CL[2][8], NL[2][8], DD[2][8];
        int CM[2][8], NM[2][8];
        float wA, wB, ZA = 0.0f, ZB = 0.0f;

        if (isF) {
            LOADC(CL, CM, 0);
            LOADC(NL, NM, 8);
            const float stj = startt[j];
            wA = __expf(CL[0][0] + stj);
            wB = __expf(CL[1][0] + stj);
            DDC();
            FSTEP2(1,false); FSTEP2(2,false); FSTEP2(3,false);
            FSTEP2(4,true);  FSTEP2(5,false); FSTEP2(6,false); FSTEP2(7,false);
            for (int c = 1; c < 32; ++c) {
                COPYNC();
                if (c < 31) LOADC(NL, NM, 8 * (c + 1));
                DDC();
                FSTEP2(0,true);  FSTEP2(1,false); FSTEP2(2,false); FSTEP2(3,false);
                FSTEP2(4,true);  FSTEP2(5,false); FSTEP2(6,false); FSTEP2(7,false);
            }
            if (vA) { ws[(size_t)qA * REC + j] = wA; if (j == 0) ws[(size_t)qA * REC + 17] = ZA; }
            if (vB) { ws[(size_t)qB * REC + j] = wB; if (j == 0) ws[(size_t)qB * REC + 17] = ZB; }
        } else {
            LOADC(CL, CM, 504);
            LOADC(NL, NM, 496);
            const float ej = __expf(endt[j]);
            wA = ej; wB = ej;                       // v_{511}
            DDC();
            BSTEP2(7,true);  BSTEP2(6,false); BSTEP2(5,false); BSTEP2(4,false);
            BSTEP2(3,true);  BSTEP2(2,false); BSTEP2(1,false); BSTEP2(0,false);
            for (int c = 1; c < 32; ++c) {
                COPYNC();
                if (c < 31) LOADC(NL, NM, 504 - 8 * (c + 1));
                DDC();
                BSTEP2(7,true);  BSTEP2(6,false); BSTEP2(5,false); BSTEP2(4,false);
                BSTEP2(3,true);  BSTEP2(2,false); BSTEP2(1,false); BSTEP2(0,false);
            }
            if (vA) { ws[(size_t)qA * REC + 18 + j] = wA; if (j == 0) ws[(size_t)qA * REC + 35] = ZA; }
            if (vB) { ws[(size_t)qB * REC + 18 + j] = wB; if (j == 0) ws[(size_t)qB * REC + 35] = ZB; }
        }
    } else {
        // ======== HELPER: per-seq path score (1 seq / wave) ========
        const int s = bid - MAINB;
        const int* tp = tags + (size_t)s * S_;
        const int* mp = mask + (size_t)s * S_;
        const float* ib = inputs + (size_t)s * (S_ * T_);
        const int4* tp4 = (const int4*)tp;
        const int4* mp4 = (const int4*)mp;

        int4 t0 = tp4[2 * lane], t1 = tp4[2 * lane + 1];
        int4 m0 = mp4[2 * lane], m1 = mp4[2 * lane + 1];
        int tg[8] = {t0.x, t0.y, t0.z, t0.w, t1.x, t1.y, t1.z, t1.w};
        int mi[8] = {m0.x, m0.y, m0.z, m0.w, m1.x, m1.y, m1.z, m1.w};
        int tprev = (lane > 0) ? tp[8 * lane - 1] : 0;

        float e = 0.0f, tr = 0.0f;
        int ms = 0;
#pragma unroll
        for (int u = 0; u < 8; ++u) {
            int t = 8 * lane + u;
            float mf = (float)mi[u];
            float gate = (t <= S_ - 2) ? mf : 0.0f;
            e = fmaf(gate, ib[(size_t)t * T_ + tg[u]], e);
            int pt = (u == 0) ? tprev : tg[u - 1];
            float tv = tl[pt * T_ + tg[u]];
            tr = fmaf((t >= 1) ? mf : 0.0f, tv, tr);
            ms += mi[u];
        }
        for (int d = 1; d < 64; d <<= 1) {
            e  += __shfl_xor(e, d);
            tr += __shfl_xor(tr, d);
            ms += __shfl_xor(ms, d);
        }
        if (lane == 0) {
            int li = ms - 1; if (li < 0) li = 0;
            int lt = tp[li];
            float ml = (float)mp[S_ - 1];
            float lin = ib[(size_t)(S_ - 1) * T_ + lt];
            float sc = startt[tp[0]] + tr + e + endt[lt] + lin * ml;
            ws[(size_t)s * REC + 36] = sc;
        }
    }
}

__global__ __launch_bounds__(256) void crf_final(const float* __restrict__ ws,
                                                 float* __restrict__ out)
{
    __shared__ float sm[256];
    const int tid = (int)threadIdx.x;
    float a = 0.0f;
    for (int s = tid; s < B_; s += 256) {
        const float* r = ws + (size_t)s * REC;
        float dot = 0.0f;
#pragma unroll
        for (int i = 0; i < T_; ++i) dot = fmaf(r[i], r[18 + i], dot);
        a += r[36] - (r[17] + r[35] + __logf(dot));
    }
    sm[tid] = a;
    __syncthreads();
    for (int k = 128; k >= 1; k >>= 1) {
        if (tid < k) sm[tid] += sm[tid + k];
        __syncthreads();
    }
    if (tid == 0) out[0] = sm[0];
}

extern "C" void kernel_launch(void* const* d_in, const int* in_sizes, int n_in,
                              void* d_out, int out_size, void* d_ws, size_t ws_size,
                              hipStream_t stream)
{
    const float* inputs = (const float*)d_in[0];
    const int*   tags   = (const int*)d_in[1];
    const int*   mask   = (const int*)d_in[2];
    const float* trans  = (const float*)d_in[3];
    const float* startt = (const float*)d_in[4];
    const float* endt   = (const float*)d_in[5];
    float* out = (float*)d_out;
    float* ws  = (float*)d_ws;

    crf_fused<<<MAINB + B_, 64, 0, stream>>>(inputs, tags, mask, trans,
                                             startt, endt, ws);
    crf_final<<<1, 256, 0, stream>>>(ws, out);
}

// Round 6
// 78.380 us; speedup vs baseline: 2.0405x; 1.0564x over previous
//
#include <hip/hip_runtime.h>

#define B_ 2048
#define S_ 512
#define T_ 17
#define REC 40
#define FWDB 64          // fwd main blocks (32 seqs each)
#define MAINB 128        // fwd + bwd mains; helpers follow

typedef float v16f __attribute__((ext_vector_type(16)));
typedef short v8s  __attribute__((ext_vector_type(8)));
typedef float f4u  __attribute__((ext_vector_type(4), aligned(4)));

union frag_u { unsigned u[4]; v8s v; };

static __device__ inline unsigned pkbf(float lo, float hi) {
    unsigned r;
    asm volatile("v_cvt_pk_bf16_f32 %0, %1, %2" : "=v"(r) : "v"(lo), "v"(hi));
    return r;
}

// ---- load one 4-step chunk of logits (lane's 9 rows) + masks ----
#define LOADK(Q0, Q1, SS, MM, T0_) do {                                      \
    const float* bp_ = ip + (size_t)(T0_) * T_;                              \
    _Pragma("unroll") for (int u_ = 0; u_ < 4; ++u_) {                       \
        Q0[u_] = *(const f4u*)(bp_ + u_ * T_ + 4 * h);                       \
        Q1[u_] = *(const f4u*)(bp_ + u_ * T_ + 8 + 4 * h);                   \
        SS[u_] = bp_[u_ * T_ + 16];                                          \
    }                                                                        \
    MM = *(const int4*)(mp + (T0_));                                         \
} while (0)

// ---- W (f32, D-layout rows) -> B-fragments, cross-half via shfl_xor ----
#define PACKB(S0,S1,S2,S3,S4,S5,S6,S7,S8, B1, B2) do {                       \
    unsigned P0_ = pkbf(S0, S1), P1_ = pkbf(S2, S3);                         \
    unsigned R0_ = pkbf(S4, S5), R1_ = pkbf(S6, S7);                         \
    unsigned sP0_ = (unsigned)__shfl_xor((int)P0_, 32);                      \
    unsigned sP1_ = (unsigned)__shfl_xor((int)P1_, 32);                      \
    unsigned sR0_ = (unsigned)__shfl_xor((int)R0_, 32);                      \
    unsigned sR1_ = (unsigned)__shfl_xor((int)R1_, 32);                      \
    B1.u[0] = h ? sR0_ : P0_;  B1.u[1] = h ? sR1_ : P1_;                     \
    B1.u[2] = h ? R0_ : sP0_;  B1.u[3] = h ? R1_ : sP1_;                     \
    B2.u[0] = h ? 0u : pkbf(S8, 0.0f);                                       \
    B2.u[1] = 0u; B2.u[2] = 0u; B2.u[3] = 0u;                                \
} while (0)

// ---- forward step: W' = (E^T W) o d, mask-gated ----
#define FSTEP(Q0u, Q1u, Su, Mu) do {                                         \
    frag_u B1_, B2_;                                                         \
    PACKB(W0,W1,W2,W3,W4,W5,W6,W7,W8, B1_, B2_);                             \
    v16f acc_ = zacc;                                                        \
    acc_ = __builtin_amdgcn_mfma_f32_32x32x16_bf16(A1.v, B1_.v, acc_,0,0,0); \
    acc_ = __builtin_amdgcn_mfma_f32_32x32x16_bf16(A2.v, B2_.v, acc_,0,0,0); \
    float d0_=__expf((Q0u).x), d1_=__expf((Q0u).y);                          \
    float d2_=__expf((Q0u).z), d3_=__expf((Q0u).w);                          \
    float d4_=__expf((Q1u).x), d5_=__expf((Q1u).y);                          \
    float d6_=__expf((Q1u).z), d7_=__expf((Q1u).w);                          \
    float d8_ = h ? 0.0f : __expf(Su);                                       \
    float n0_=acc_[0]*d0_, n1_=acc_[1]*d1_, n2_=acc_[2]*d2_, n3_=acc_[3]*d3_;\
    float n4_=acc_[4]*d4_, n5_=acc_[5]*d5_, n6_=acc_[6]*d6_, n7_=acc_[7]*d7_;\
    float n8_=acc_[8]*d8_;                                                   \
    if (__all((Mu) != 0)) {                                                  \
        W0=n0_; W1=n1_; W2=n2_; W3=n3_; W4=n4_;                              \
        W5=n5_; W6=n6_; W7=n7_; W8=n8_;                                      \
    } else {                                                                 \
        bool bm_ = (Mu) != 0;                                                \
        W0=bm_?n0_:W0; W1=bm_?n1_:W1; W2=bm_?n2_:W2; W3=bm_?n3_:W3;          \
        W4=bm_?n4_:W4; W5=bm_?n5_:W5; W6=bm_?n6_:W6; W7=bm_?n7_:W7;          \
        W8=bm_?n8_:W8;                                                       \
    }                                                                        \
} while (0)

// ---- backward step: v' = E (d o v), mask-gated ----
#define BSTEP(Q0u, Q1u, Su, Mu) do {                                         \
    float d0_=__expf((Q0u).x), d1_=__expf((Q0u).y);                          \
    float d2_=__expf((Q0u).z), d3_=__expf((Q0u).w);                          \
    float d4_=__expf((Q1u).x), d5_=__expf((Q1u).y);                          \
    float d6_=__expf((Q1u).z), d7_=__expf((Q1u).w);                          \
    float d8_ = h ? 0.0f : __expf(Su);                                       \
    float U0_=W0*d0_, U1_=W1*d1_, U2_=W2*d2_, U3_=W3*d3_;                    \
    float U4_=W4*d4_, U5_=W5*d5_, U6_=W6*d6_, U7_=W7*d7_, U8_=W8*d8_;        \
    frag_u B1_, B2_;                                                         \
    PACKB(U0_,U1_,U2_,U3_,U4_,U5_,U6_,U7_,U8_, B1_, B2_);                    \
    v16f acc_ = zacc;                                                        \
    acc_ = __builtin_amdgcn_mfma_f32_32x32x16_bf16(A1.v, B1_.v, acc_,0,0,0); \
    acc_ = __builtin_amdgcn_mfma_f32_32x32x16_bf16(A2.v, B2_.v, acc_,0,0,0); \
    if (__all((Mu) != 0)) {                                                  \
        W0=acc_[0]; W1=acc_[1]; W2=acc_[2]; W3=acc_[3]; W4=acc_[4];          \
        W5=acc_[5]; W6=acc_[6]; W7=acc_[7]; W8=acc_[8];                      \
    } else {                                                                 \
        bool bm_ = (Mu) != 0;                                                \
        W0=bm_?acc_[0]:W0; W1=bm_?acc_[1]:W1; W2=bm_?acc_[2]:W2;             \
        W3=bm_?acc_[3]:W3; W4=bm_?acc_[4]:W4; W5=bm_?acc_[5]:W5;             \
        W6=bm_?acc_[6]:W6; W7=bm_?acc_[7]:W7; W8=bm_?acc_[8]:W8;             \
    }                                                                        \
} while (0)

#define RENORM() do {                                                        \
    float M_ = fmaxf(fmaxf(fmaxf(W0,W1),fmaxf(W2,W3)),                       \
                     fmaxf(fmaxf(W4,W5),fmaxf(fmaxf(W6,W7),W8)));            \
    M_ = fmaxf(M_, __shfl_xor(M_, 32));                                      \
    float r_ = 1.0f / M_;                                                    \
    Z += __logf(M_);                                                         \
    W0*=r_; W1*=r_; W2*=r_; W3*=r_; W4*=r_;                                  \
    W5*=r_; W6*=r_; W7*=r_; W8*=r_;                                          \
} while (0)

#define FCHUNK(Q0a, Q1a, Sa, Ma) do {                                        \
    FSTEP(Q0a[0], Q1a[0], Sa[0], (Ma).x);                                    \
    FSTEP(Q0a[1], Q1a[1], Sa[1], (Ma).y);                                    \
    FSTEP(Q0a[2], Q1a[2], Sa[2], (Ma).z);                                    \
    FSTEP(Q0a[3], Q1a[3], Sa[3], (Ma).w);                                    \
    RENORM();                                                                \
} while (0)

#define BCHUNK(Q0a, Q1a, Sa, Ma) do {                                        \
    BSTEP(Q0a[3], Q1a[3], Sa[3], (Ma).w);                                    \
    BSTEP(Q0a[2], Q1a[2], Sa[2], (Ma).z);                                    \
    BSTEP(Q0a[1], Q1a[1], Sa[1], (Ma).y);                                    \
    BSTEP(Q0a[0], Q1a[0], Sa[0], (Ma).x);                                    \
    RENORM();                                                                \
} while (0)

__global__ __launch_bounds__(64) void crf_fused(
    const float* __restrict__ inputs,   // [B,S,T]
    const int*   __restrict__ tags,     // [B,S]
    const int*   __restrict__ mask,     // [B,S]
    const float* __restrict__ trans,    // [T,T]
    const float* __restrict__ startt,   // [T]
    const float* __restrict__ endt,     // [T]
    float* __restrict__ ws)             // [B][REC]
{
    __shared__ float tl[T_ * T_];
    const int lane = (int)threadIdx.x;
    const int bid = (int)blockIdx.x;
    for (int k = lane; k < T_ * T_; k += 64) tl[k] = trans[k];
    __syncthreads();

    if (bid < MAINB) {
        // ===== MAIN: MFMA scaled recurrence, 32 seqs per wave =====
        const bool isF = (bid < FWDB);
        const int h = lane >> 5;        // half: selects D-rows / B-k range
        const int col = lane & 31;      // seq column (and A row)
        const int seq = (isF ? bid : bid - FWDB) * 32 + col;

        // A fragments: fwd A = E^T padded to 32x32, bwd A = E padded.
        // A-frag: row = lane&31, k = 8*h + i (bf16 pairs lo/hi per u32).
        frag_u A1, A2;
#pragma unroll
        for (int wd = 0; wd < 4; ++wd) {
            const int k0 = 8 * h + 2 * wd, k1 = k0 + 1;   // k0,k1 <= 15 < 17
            float e0 = 0.0f, e1 = 0.0f;
            if (col < 17) {
                e0 = isF ? __expf(tl[k0 * T_ + col]) : __expf(tl[col * T_ + k0]);
                e1 = isF ? __expf(tl[k1 * T_ + col]) : __expf(tl[col * T_ + k1]);
            }
            A1.u[wd] = pkbf(e0, e1);
        }
        {
            float e16 = 0.0f;           // second K-half: only global k==16 real
            if (h == 0 && col < 17)
                e16 = isF ? __expf(tl[16 * T_ + col]) : __expf(tl[col * T_ + 16]);
            A2.u[0] = pkbf(e16, 0.0f);
            A2.u[1] = 0u; A2.u[2] = 0u; A2.u[3] = 0u;
        }

        v16f zacc;
#pragma unroll
        for (int r = 0; r < 16; ++r) zacc[r] = 0.0f;

        const float* ip = inputs + (size_t)seq * (S_ * T_);
        const int*   mp = mask + (size_t)seq * S_;

        // lane's real rows: 4h..4h+3 (W0-3), 8+4h..11+4h (W4-7), 16 if h==0 (W8)
        float W0, W1, W2, W3, W4, W5, W6, W7, W8, Z = 0.0f;

        f4u X0[4], X1[4]; float XS[4]; int4 XM;
        f4u Y0[4], Y1[4]; float YS[4]; int4 YM;

        if (isF) {
            LOADK(X0, X1, XS, XM, 0);
            LOADK(Y0, Y1, YS, YM, 4);
            {   // init: alpha0 = exp(logit0 + start)
                f4u s0 = *(const f4u*)(startt + 4 * h);
                f4u s1 = *(const f4u*)(startt + 8 + 4 * h);
                float s16 = startt[16];
                W0 = __expf(X0[0].x + s0.x); W1 = __expf(X0[0].y + s0.y);
                W2 = __expf(X0[0].z + s0.z); W3 = __expf(X0[0].w + s0.w);
                W4 = __expf(X1[0].x + s1.x); W5 = __expf(X1[0].y + s1.y);
                W6 = __expf(X1[0].z + s1.z); W7 = __expf(X1[0].w + s1.w);
                W8 = h ? 0.0f : __expf(XS[0] + s16);
            }
            FSTEP(X0[1], X1[1], XS[1], XM.y);
            FSTEP(X0[2], X1[2], XS[2], XM.z);
            FSTEP(X0[3], X1[3], XS[3], XM.w);
            RENORM();
            LOADK(X0, X1, XS, XM, 8);
            FCHUNK(Y0, Y1, YS, YM);                       // chunk 1 (t 4..7)
            for (int cp = 1; cp < 31; ++cp) {
                LOADK(Y0, Y1, YS, YM, 8 * cp + 4);        // chunk 2cp+1
                FCHUNK(X0, X1, XS, XM);                   // chunk 2cp
                LOADK(X0, X1, XS, XM, 8 * cp + 8);        // chunk 2cp+2
                FCHUNK(Y0, Y1, YS, YM);                   // chunk 2cp+1
            }
            LOADK(Y0, Y1, YS, YM, 252);                   // chunk 63
            FCHUNK(X0, X1, XS, XM);                       // chunk 62
            FCHUNK(Y0, Y1, YS, YM);                       // chunk 63 -> alpha_255
            float* rec = ws + (size_t)seq * REC;
            rec[4*h+0] = W0; rec[4*h+1] = W1; rec[4*h+2] = W2; rec[4*h+3] = W3;
            rec[8+4*h+0] = W4; rec[8+4*h+1] = W5; rec[8+4*h+2] = W6; rec[8+4*h+3] = W7;
            if (h == 0) { rec[16] = W8; rec[17] = Z; }
        } else {
            LOADK(X0, X1, XS, XM, 508);
            LOADK(Y0, Y1, YS, YM, 504);
            {   // init: v_511 = exp(end)
                f4u e0 = *(const f4u*)(endt + 4 * h);
                f4u e1 = *(const f4u*)(endt + 8 + 4 * h);
                W0 = __expf(e0.x); W1 = __expf(e0.y);
                W2 = __expf(e0.z); W3 = __expf(e0.w);
                W4 = __expf(e1.x); W5 = __expf(e1.y);
                W6 = __expf(e1.z); W7 = __expf(e1.w);
                W8 = h ? 0.0f : __expf(endt[16]);
            }
            BCHUNK(X0, X1, XS, XM);                       // t 511..508
            LOADK(X0, X1, XS, XM, 500);                   // chunk 2
            BCHUNK(Y0, Y1, YS, YM);                       // t 507..504
            for (int cp = 1; cp < 31; ++cp) {
                LOADK(Y0, Y1, YS, YM, 508 - 8 * cp - 4);  // chunk 2cp+1
                BCHUNK(X0, X1, XS, XM);                   // chunk 2cp
                LOADK(X0, X1, XS, XM, 508 - 8 * cp - 8);  // chunk 2cp+2
                BCHUNK(Y0, Y1, YS, YM);                   // chunk 2cp+1
            }
            LOADK(Y0, Y1, YS, YM, 256);                   // chunk 63
            BCHUNK(X0, X1, XS, XM);                       // chunk 62 (t 263..260)
            BCHUNK(Y0, Y1, YS, YM);                       // chunk 63 -> v_255
            float* rec = ws + (size_t)seq * REC;
            rec[18+4*h+0] = W0; rec[18+4*h+1] = W1;
            rec[18+4*h+2] = W2; rec[18+4*h+3] = W3;
            rec[18+8+4*h+0] = W4; rec[18+8+4*h+1] = W5;
            rec[18+8+4*h+2] = W6; rec[18+8+4*h+3] = W7;
            if (h == 0) { rec[34] = W8; rec[35] = Z; }
        }
    } else {
        // ===== HELPER: per-seq path score (1 seq / wave) — r5-validated =====
        const int s = bid - MAINB;
        const int* tp = tags + (size_t)s * S_;
        const int* mp = mask + (size_t)s * S_;
        const float* ib = inputs + (size_t)s * (S_ * T_);
        const int4* tp4 = (const int4*)tp;
        const int4* mp4 = (const int4*)mp;

        int4 t0 = tp4[2 * lane], t1 = tp4[2 * lane + 1];
        int4 m0 = mp4[2 * lane], m1 = mp4[2 * lane + 1];
        int tg[8] = {t0.x, t0.y, t0.z, t0.w, t1.x, t1.y, t1.z, t1.w};
        int mi[8] = {m0.x, m0.y, m0.z, m0.w, m1.x, m1.y, m1.z, m1.w};
        int tprev = (lane > 0) ? tp[8 * lane - 1] : 0;

        float e = 0.0f, tr = 0.0f;
        int ms = 0;
#pragma unroll
        for (int u = 0; u < 8; ++u) {
            int t = 8 * lane + u;
            float mf = (float)mi[u];
            float gate = (t <= S_ - 2) ? mf : 0.0f;
            e = fmaf(gate, ib[(size_t)t * T_ + tg[u]], e);
            int pt = (u == 0) ? tprev : tg[u - 1];
            float tv = tl[pt * T_ + tg[u]];
            tr = fmaf((t >= 1) ? mf : 0.0f, tv, tr);
            ms += mi[u];
        }
        for (int d = 1; d < 64; d <<= 1) {
            e  += __shfl_xor(e, d);
            tr += __shfl_xor(tr, d);
            ms += __shfl_xor(ms, d);
        }
        if (lane == 0) {
            int li = ms - 1; if (li < 0) li = 0;
            int lt = tp[li];
            float ml = (float)mp[S_ - 1];
            float lin = ib[(size_t)(S_ - 1) * T_ + lt];
            float sc = startt[tp[0]] + tr + e + endt[lt] + lin * ml;
            ws[(size_t)s * REC + 36] = sc;
        }
    }
}

__global__ __launch_bounds__(256) void crf_final(const float* __restrict__ ws,
                                                 float* __restrict__ out)
{
    __shared__ float sm[256];
    const int tid = (int)threadIdx.x;
    float a = 0.0f;
    for (int s = tid; s < B_; s += 256) {
        const float* r = ws + (size_t)s * REC;
        float dot = 0.0f;
#pragma unroll
        for (int i = 0; i < T_; ++i) dot = fmaf(r[i], r[18 + i], dot);
        a += r[36] - (r[17] + r[35] + __logf(dot));
    }
    sm[tid] = a;
    __syncthreads();
    for (int k = 128; k >= 1; k >>= 1) {
        if (tid < k) sm[tid] += sm[tid + k];
        __syncthreads();
    }
    if (tid == 0) out[0] = sm[0];
}

extern "C" void kernel_launch(void* const* d_in, const int* in_sizes, int n_in,
                              void* d_out, int out_size, void* d_ws, size_t ws_size,
                              hipStream_t stream)
{
    const float* inputs = (const float*)d_in[0];
    const int*   tags   = (const int*)d_in[1];
    const int*   mask   = (const int*)d_in[2];
    const float* trans  = (const float*)d_in[3];
    const float* startt = (const float*)d_in[4];
    const float* endt   = (const float*)d_in[5];
    float* out = (float*)d_out;
    float* ws  = (float*)d_ws;

    crf_fused<<<MAINB + B_, 64, 0, stream>>>(inputs, tags, mask, trans,
                                             startt, endt, ws);
    crf_final<<<1, 256, 0, stream>>>(ws, out);
}

// Round 8
// 67.933 us; speedup vs baseline: 2.3544x; 1.1538x over previous
//
#include <hip/hip_runtime.h>

#define B_ 2048
#define S_ 512
#define T_ 17
#define REC 40
#define FWDB 64          // fwd main blocks (32 seqs each)
#define MAINB 128        // fwd + bwd mains; helpers follow

typedef float v16f __attribute__((ext_vector_type(16)));
typedef short v8s  __attribute__((ext_vector_type(8)));
typedef float f4u  __attribute__((ext_vector_type(4), aligned(4)));

union frag_u { unsigned u[4]; v8s v; };

static __device__ inline unsigned pkbf(float lo, float hi) {
    unsigned r;
    asm volatile("v_cvt_pk_bf16_f32 %0, %1, %2" : "=v"(r) : "v"(lo), "v"(hi));
    return r;
}

// ---- load one 4-step chunk of logits (lane's 9 rows) + masks ----
#define LOADK(Q0, Q1, SS, MM, T0_) do {                                      \
    const float* bp_ = ip + (size_t)(T0_) * T_;                              \
    _Pragma("unroll") for (int u_ = 0; u_ < 4; ++u_) {                       \
        Q0[u_] = *(const f4u*)(bp_ + u_ * T_ + 4 * h);                       \
        Q1[u_] = *(const f4u*)(bp_ + u_ * T_ + 8 + 4 * h);                   \
        SS[u_] = bp_[u_ * T_ + 16];                                          \
    }                                                                        \
    MM = *(const int4*)(mp + (T0_));                                         \
} while (0)

// ---- pack W rows 0..15 (both halves) into B-fragment via permlane32_swap ----
#define PACKB(S0,S1,S2,S3,S4,S5,S6,S7, BOUT) do {                            \
    unsigned P0_ = pkbf(S0, S1), P1_ = pkbf(S2, S3);                         \
    unsigned R0_ = pkbf(S4, S5), R1_ = pkbf(S6, S7);                         \
    auto s0_ = __builtin_amdgcn_permlane32_swap(P0_, R0_, false, false);     \
    auto s1_ = __builtin_amdgcn_permlane32_swap(P1_, R1_, false, false);     \
    BOUT.u[0] = s0_[0]; BOUT.u[1] = s1_[0];                                  \
    BOUT.u[2] = s0_[1]; BOUT.u[3] = s1_[1];                                  \
} while (0)

#define W16SWAP() do {                                                       \
    auto rw_ = __builtin_amdgcn_permlane32_swap(__float_as_uint(W8),         \
                                                __float_as_uint(W8),         \
                                                false, false);               \
    w16 = __uint_as_float(rw_[0]);                                           \
} while (0)

// ---- forward step: W' = (E^T W) o d, mask-gated ----
#define FSTEP(Q0u, Q1u, Su, Mu) do {                                         \
    frag_u Bf_;                                                              \
    PACKB(W0,W1,W2,W3,W4,W5,W6,W7, Bf_);                                     \
    v16f acc_ = __builtin_amdgcn_mfma_f32_32x32x16_bf16(A1.v, Bf_.v, zacc,0,0,0); \
    float d0_=__expf((Q0u).x), d1_=__expf((Q0u).y);                          \
    float d2_=__expf((Q0u).z), d3_=__expf((Q0u).w);                          \
    float d4_=__expf((Q1u).x), d5_=__expf((Q1u).y);                          \
    float d6_=__expf((Q1u).z), d7_=__expf((Q1u).w);                          \
    float d8_=__expf(Su);                                                    \
    bool bm_ = (Mu) != 0;                                                    \
    float n0_ = fmaf(E16[0], w16, acc_[0]) * d0_;                            \
    float n1_ = fmaf(E16[1], w16, acc_[1]) * d1_;                            \
    float n2_ = fmaf(E16[2], w16, acc_[2]) * d2_;                            \
    float n3_ = fmaf(E16[3], w16, acc_[3]) * d3_;                            \
    float n4_ = fmaf(E16[4], w16, acc_[4]) * d4_;                            \
    float n5_ = fmaf(E16[5], w16, acc_[5]) * d5_;                            \
    float n6_ = fmaf(E16[6], w16, acc_[6]) * d6_;                            \
    float n7_ = fmaf(E16[7], w16, acc_[7]) * d7_;                            \
    float n8_ = fmaf(E16[8], w16, acc_[8]) * d8_;                            \
    W0=bm_?n0_:W0; W1=bm_?n1_:W1; W2=bm_?n2_:W2; W3=bm_?n3_:W3;              \
    W4=bm_?n4_:W4; W5=bm_?n5_:W5; W6=bm_?n6_:W6; W7=bm_?n7_:W7;              \
    W8=bm_?n8_:W8;                                                           \
    W16SWAP();                                                               \
} while (0)

// ---- backward step: v' = E (d o v), mask-gated ----
#define BSTEP(Q0u, Q1u, Su, Mu) do {                                         \
    float d0_=__expf((Q0u).x), d1_=__expf((Q0u).y);                          \
    float d2_=__expf((Q0u).z), d3_=__expf((Q0u).w);                          \
    float d4_=__expf((Q1u).x), d5_=__expf((Q1u).y);                          \
    float d6_=__expf((Q1u).z), d7_=__expf((Q1u).w);                          \
    float d8_=__expf(Su);                                                    \
    float U16_ = w16 * d8_;                                                  \
    frag_u Bf_;                                                              \
    PACKB(W0*d0_, W1*d1_, W2*d2_, W3*d3_,                                    \
          W4*d4_, W5*d5_, W6*d6_, W7*d7_, Bf_);                              \
    v16f acc_ = __builtin_amdgcn_mfma_f32_32x32x16_bf16(A1.v, Bf_.v, zacc,0,0,0); \
    bool bm_ = (Mu) != 0;                                                    \
    float n0_ = fmaf(E16[0], U16_, acc_[0]);                                 \
    float n1_ = fmaf(E16[1], U16_, acc_[1]);                                 \
    float n2_ = fmaf(E16[2], U16_, acc_[2]);                                 \
    float n3_ = fmaf(E16[3], U16_, acc_[3]);                                 \
    float n4_ = fmaf(E16[4], U16_, acc_[4]);                                 \
    float n5_ = fmaf(E16[5], U16_, acc_[5]);                                 \
    float n6_ = fmaf(E16[6], U16_, acc_[6]);                                 \
    float n7_ = fmaf(E16[7], U16_, acc_[7]);                                 \
    float n8_ = fmaf(E16[8], U16_, acc_[8]);                                 \
    W0=bm_?n0_:W0; W1=bm_?n1_:W1; W2=bm_?n2_:W2; W3=bm_?n3_:W3;              \
    W4=bm_?n4_:W4; W5=bm_?n5_:W5; W6=bm_?n6_:W6; W7=bm_?n7_:W7;              \
    W8=bm_?n8_:W8;                                                           \
    W16SWAP();                                                               \
} while (0)

#define RENORM() do {                                                        \
    float M_ = fmaxf(fmaxf(fmaxf(W0,W1),fmaxf(W2,W3)),                       \
                     fmaxf(fmaxf(W4,W5),fmaxf(fmaxf(W6,W7),W8)));            \
    auto rm_ = __builtin_amdgcn_permlane32_swap(__float_as_uint(M_),         \
                                                __float_as_uint(M_),         \
                                                false, false);               \
    M_ = fmaxf(__uint_as_float(rm_[0]), __uint_as_float(rm_[1]));            \
    float r_ = 1.0f / M_;                                                    \
    Z += __logf(M_);                                                         \
    W0*=r_; W1*=r_; W2*=r_; W3*=r_; W4*=r_;                                  \
    W5*=r_; W6*=r_; W7*=r_; W8*=r_; w16*=r_;                                 \
} while (0)

#define FCHUNK(Q0a, Q1a, Sa, Ma) do {                                        \
    FSTEP(Q0a[0], Q1a[0], Sa[0], (Ma).x);                                    \
    FSTEP(Q0a[1], Q1a[1], Sa[1], (Ma).y);                                    \
    FSTEP(Q0a[2], Q1a[2], Sa[2], (Ma).z);                                    \
    FSTEP(Q0a[3], Q1a[3], Sa[3], (Ma).w);                                    \
    RENORM();                                                                \
} while (0)

#define BCHUNK(Q0a, Q1a, Sa, Ma) do {                                        \
    BSTEP(Q0a[3], Q1a[3], Sa[3], (Ma).w);                                    \
    BSTEP(Q0a[2], Q1a[2], Sa[2], (Ma).z);                                    \
    BSTEP(Q0a[1], Q1a[1], Sa[1], (Ma).y);                                    \
    BSTEP(Q0a[0], Q1a[0], Sa[0], (Ma).x);                                    \
    RENORM();                                                                \
} while (0)

__global__ __launch_bounds__(64) void crf_fused(
    const float* __restrict__ inputs,   // [B,S,T]
    const int*   __restrict__ tags,     // [B,S]
    const int*   __restrict__ mask,     // [B,S]
    const float* __restrict__ trans,    // [T,T]
    const float* __restrict__ startt,   // [T]
    const float* __restrict__ endt,     // [T]
    float* __restrict__ ws)             // [B][REC]
{
    __shared__ float tl[T_ * T_];
    const int lane = (int)threadIdx.x;
    const int bid = (int)blockIdx.x;
    for (int k = lane; k < T_ * T_; k += 64) tl[k] = trans[k];
    __syncthreads();

    if (bid < MAINB) {
        // ===== MAIN: MFMA scaled recurrence, 32 seqs per wave =====
        const bool isF = (bid < FWDB);
        const int h = lane >> 5;        // half
        const int col = lane & 31;      // seq column (and A row)
        const int seq = (isF ? bid : bid - FWDB) * 32 + col;

        // A fragment (k=0..15 only): fwd A = E^T padded, bwd A = E padded.
        frag_u A1;
#pragma unroll
        for (int wd = 0; wd < 4; ++wd) {
            const int k0 = 8 * h + 2 * wd, k1 = k0 + 1;
            float e0 = 0.0f, e1 = 0.0f;
            if (col < 17) {
                e0 = isF ? __expf(tl[k0 * T_ + col]) : __expf(tl[col * T_ + k0]);
                e1 = isF ? __expf(tl[k1 * T_ + col]) : __expf(tl[col * T_ + k1]);
            }
            A1.u[wd] = pkbf(e0, e1);
        }
        // k=16 rank-1 coefficients, per lane's 9 rows
        float E16[9];
#pragma unroll
        for (int k = 0; k < 4; ++k) {
            const int r0 = 4 * h + k, r1 = 8 + 4 * h + k;
            E16[k]     = __expf(isF ? tl[16 * T_ + r0] : tl[r0 * T_ + 16]);
            E16[4 + k] = __expf(isF ? tl[16 * T_ + r1] : tl[r1 * T_ + 16]);
        }
        E16[8] = (h == 0) ? __expf(tl[16 * T_ + 16]) : 0.0f;

        v16f zacc;
#pragma unroll
        for (int r = 0; r < 16; ++r) zacc[r] = 0.0f;

        const float* ip = inputs + (size_t)seq * (S_ * T_);
        const int*   mp = mask + (size_t)seq * S_;

        float W0, W1, W2, W3, W4, W5, W6, W7, W8, w16, Z = 0.0f;

        f4u X0[4], X1[4]; float XS[4]; int4 XM;
        f4u Y0[4], Y1[4]; float YS[4]; int4 YM;

        if (isF) {
            LOADK(X0, X1, XS, XM, 0);
            LOADK(Y0, Y1, YS, YM, 4);
            {   // init: alpha0 = exp(logit0 + start)
                f4u s0 = *(const f4u*)(startt + 4 * h);
                f4u s1 = *(const f4u*)(startt + 8 + 4 * h);
                W0 = __expf(X0[0].x + s0.x); W1 = __expf(X0[0].y + s0.y);
                W2 = __expf(X0[0].z + s0.z); W3 = __expf(X0[0].w + s0.w);
                W4 = __expf(X1[0].x + s1.x); W5 = __expf(X1[0].y + s1.y);
                W6 = __expf(X1[0].z + s1.z); W7 = __expf(X1[0].w + s1.w);
                W8 = h ? 0.0f : __expf(XS[0] + startt[16]);
                W16SWAP();
            }
            FSTEP(X0[1], X1[1], XS[1], XM.y);
            FSTEP(X0[2], X1[2], XS[2], XM.z);
            FSTEP(X0[3], X1[3], XS[3], XM.w);
            RENORM();
            LOADK(X0, X1, XS, XM, 8);
            FCHUNK(Y0, Y1, YS, YM);                       // chunk 1 (t 4..7)
            for (int cp = 1; cp < 31; ++cp) {
                LOADK(Y0, Y1, YS, YM, 8 * cp + 4);        // chunk 2cp+1
                FCHUNK(X0, X1, XS, XM);                   // chunk 2cp
                LOADK(X0, X1, XS, XM, 8 * cp + 8);        // chunk 2cp+2
                FCHUNK(Y0, Y1, YS, YM);                   // chunk 2cp+1
            }
            LOADK(Y0, Y1, YS, YM, 252);                   // chunk 63
            FCHUNK(X0, X1, XS, XM);                       // chunk 62
            FCHUNK(Y0, Y1, YS, YM);                       // chunk 63 -> alpha_255
            float* rec = ws + (size_t)seq * REC;
            rec[4*h+0] = W0; rec[4*h+1] = W1; rec[4*h+2] = W2; rec[4*h+3] = W3;
            rec[8+4*h+0] = W4; rec[8+4*h+1] = W5; rec[8+4*h+2] = W6; rec[8+4*h+3] = W7;
            if (h == 0) { rec[16] = W8; rec[17] = Z; }
        } else {
            LOADK(X0, X1, XS, XM, 508);
            LOADK(Y0, Y1, YS, YM, 504);
            {   // init: v_511 = exp(end)
                f4u e0 = *(const f4u*)(endt + 4 * h);
                f4u e1 = *(const f4u*)(endt + 8 + 4 * h);
                W0 = __expf(e0.x); W1 = __expf(e0.y);
                W2 = __expf(e0.z); W3 = __expf(e0.w);
                W4 = __expf(e1.x); W5 = __expf(e1.y);
                W6 = __expf(e1.z); W7 = __expf(e1.w);
                W8 = h ? 0.0f : __expf(endt[16]);
                W16SWAP();
            }
            BCHUNK(X0, X1, XS, XM);                       // t 511..508
            LOADK(X0, X1, XS, XM, 500);                   // chunk 2
            BCHUNK(Y0, Y1, YS, YM);                       // t 507..504
            for (int cp = 1; cp < 31; ++cp) {
                LOADK(Y0, Y1, YS, YM, 508 - 8 * cp - 4);  // chunk 2cp+1
                BCHUNK(X0, X1, XS, XM);                   // chunk 2cp
                LOADK(X0, X1, XS, XM, 508 - 8 * cp - 8);  // chunk 2cp+2
                BCHUNK(Y0, Y1, YS, YM);                   // chunk 2cp+1
            }
            LOADK(Y0, Y1, YS, YM, 256);                   // chunk 63
            BCHUNK(X0, X1, XS, XM);                       // chunk 62 (t 263..260)
            BCHUNK(Y0, Y1, YS, YM);                       // chunk 63 -> v_255
            float* rec = ws + (size_t)seq * REC;
            rec[18+4*h+0] = W0; rec[18+4*h+1] = W1;
            rec[18+4*h+2] = W2; rec[18+4*h+3] = W3;
            rec[18+8+4*h+0] = W4; rec[18+8+4*h+1] = W5;
            rec[18+8+4*h+2] = W6; rec[18+8+4*h+3] = W7;
            if (h == 0) { rec[34] = W8; rec[35] = Z; }
        }
    } else {
        // ===== HELPER: per-seq path score (1 seq / wave) — r5/r6-validated =====
        const int s = bid - MAINB;
        const int* tp = tags + (size_t)s * S_;
        const int* mp = mask + (size_t)s * S_;
        const float* ib = inputs + (size_t)s * (S_ * T_);
        const int4* tp4 = (const int4*)tp;
        const int4* mp4 = (const int4*)mp;

        int4 t0 = tp4[2 * lane], t1 = tp4[2 * lane + 1];
        int4 m0 = mp4[2 * lane], m1 = mp4[2 * lane + 1];
        int tg[8] = {t0.x, t0.y, t0.z, t0.w, t1.x, t1.y, t1.z, t1.w};
        int mi[8] = {m0.x, m0.y, m0.z, m0.w, m1.x, m1.y, m1.z, m1.w};
        int tprev = (lane > 0) ? tp[8 * lane - 1] : 0;

        float e = 0.0f, tr = 0.0f;
        int ms = 0;
#pragma unroll
        for (int u = 0; u < 8; ++u) {
            int t = 8 * lane + u;
            float mf = (float)mi[u];
            float gate = (t <= S_ - 2) ? mf : 0.0f;
            e = fmaf(gate, ib[(size_t)t * T_ + tg[u]], e);
            int pt = (u == 0) ? tprev : tg[u - 1];
            float tv = tl[pt * T_ + tg[u]];
            tr = fmaf((t >= 1) ? mf : 0.0f, tv, tr);
            ms += mi[u];
        }
        for (int d = 1; d < 64; d <<= 1) {
            e  += __shfl_xor(e, d);
            tr += __shfl_xor(tr, d);
            ms += __shfl_xor(ms, d);
        }
        if (lane == 0) {
            int li = ms - 1; if (li < 0) li = 0;
            int lt = tp[li];
            float ml = (float)mp[S_ - 1];
            float lin = ib[(size_t)(S_ - 1) * T_ + lt];
            float sc = startt[tp[0]] + tr + e + endt[lt] + lin * ml;
            ws[(size_t)s * REC + 36] = sc;
        }
    }
}

__global__ __launch_bounds__(256) void crf_final(const float* __restrict__ ws,
                                                 float* __restrict__ out)
{
    __shared__ float sm[256];
    const int tid = (int)threadIdx.x;
    float a = 0.0f;
    for (int s = tid; s < B_; s += 256) {
        const float* r = ws + (size_t)s * REC;
        float dot = 0.0f;
#pragma unroll
        for (int i = 0; i < T_; ++i) dot = fmaf(r[i], r[18 + i], dot);
        a += r[36] - (r[17] + r[35] + __logf(dot));
    }
    sm[tid] = a;
    __syncthreads();
    for (int k = 128; k >= 1; k >>= 1) {
        if (tid < k) sm[tid] += sm[tid + k];
        __syncthreads();
    }
    if (tid == 0) out[0] = sm[0];
}

extern "C" void kernel_launch(void* const* d_in, const int* in_sizes, int n_in,
                              void* d_out, int out_size, void* d_ws, size_t ws_size,
                              hipStream_t stream)
{
    const float* inputs = (const float*)d_in[0];
    const int*   tags   = (const int*)d_in[1];
    const int*   mask   = (const int*)d_in[2];
    const float* trans  = (const float*)d_in[3];
    const float* startt = (const float*)d_in[4];
    const float* endt   = (const float*)d_in[5];
    float* out = (float*)d_out;
    float* ws  = (float*)d_ws;

    crf_fused<<<MAINB + B_, 64, 0, stream>>>(inputs, tags, mask, trans,
                                             startt, endt, ws);
    crf_final<<<1, 256, 0, stream>>>(ws, out);
}